// Round 1
// baseline (10137.579 us; speedup 1.0000x reference)
//
#include <hip/hip_runtime.h>
#include <math.h>

#define HH 384
#define WW 512
#define HW 196608            // 384*512
#define CHW 983040           // 5*HW
#define NTOT 7864320         // 8*CHW
#define FLOW_N 3145728       // 8*2*HW
#define OUT_FLOW_OFF 16
#define OUT_IMG_OFF (16 + FLOW_N)
#define EPS_F 1e-5f
#define INV_HW (1.0f/196608.0f)

// ---- JAX threefry2x32 (bit-exact integer path) ----
__device__ __forceinline__ void tf2x32(unsigned k0, unsigned k1,
                                       unsigned x0, unsigned x1,
                                       unsigned& o0, unsigned& o1) {
  const unsigned ks2 = k0 ^ k1 ^ 0x1BD11BDAu;
  x0 += k0; x1 += k1;
#define TFR(r) x0 += x1; x1 = (x1 << (r)) | (x1 >> (32 - (r))); x1 ^= x0;
  TFR(13) TFR(15) TFR(26) TFR(6)
  x0 += k1;  x1 += ks2 + 1u;
  TFR(17) TFR(29) TFR(16) TFR(24)
  x0 += ks2; x1 += k0 + 2u;
  TFR(13) TFR(15) TFR(26) TFR(6)
  x0 += k0;  x1 += k1 + 3u;
  TFR(17) TFR(29) TFR(16) TFR(24)
  x0 += k1;  x1 += ks2 + 4u;
  TFR(13) TFR(15) TFR(26) TFR(6)
  x0 += ks2; x1 += k0 + 5u;
#undef TFR
  o0 = x0; o1 = x1;
}

// bits -> NOISE_STD * sqrt(2) * erfinv(uniform(lo,1))   (JAX normal * 0.05)
__device__ __forceinline__ float noise_from_bits(unsigned bits) {
  const float LO = -0.99999994f;                    // nextafter(-1,0)
  float f = __uint_as_float((bits >> 9) | 0x3F800000u) - 1.0f;  // [0,1)
  float u = fmaxf(LO, f * 2.0f + LO);               // (hi-lo) rounds to 2.0f
  // XLA ErfInv f32 (Giles polynomial)
  float w = -log1pf(-u * u);
  float p;
  if (w < 5.0f) {
    w -= 2.5f;
    p = 2.81022636e-08f;
    p = p * w + 3.43273939e-07f;
    p = p * w + -3.5233877e-06f;
    p = p * w + -4.39150654e-06f;
    p = p * w + 0.00021858087f;
    p = p * w + -0.00125372503f;
    p = p * w + -0.00417768164f;
    p = p * w + 0.246640727f;
    p = p * w + 1.50140941f;
  } else {
    w = sqrtf(w) - 3.0f;
    p = -0.000200214257f;
    p = p * w + 0.000100950558f;
    p = p * w + 0.00134934322f;
    p = p * w + -0.00367342844f;
    p = p * w + 0.00573950773f;
    p = p * w + -0.0076224613f;
    p = p * w + 0.00943887047f;
    p = p * w + 1.00167406f;
    p = p * w + 2.83297682f;
  }
  float z = 1.4142135623730951f * (p * u);
  return 0.05f * z;
}

// ---- analytic grad of energy_sum wrt x at one pixel, then clipped update ----
__device__ __forceinline__ void grad_update(const float* __restrict__ X,
                                            const float* __restrict__ in2,
                                            int b, int p, int h, int w,
                                            float s0, float s1, float xn[5]) {
  const float* F0 = X + b * CHW;
  const float* F1 = F0 + HW;
  const bool wlt = (w < WW - 1), hlt = (h < HH - 1);
  float x0r = F0[p], x1r = F1[p];
  float f00 = 80.0f * x0r, f10 = 80.0f * x1r;
  float dxc0 = 0.f, dxc1 = 0.f, dyc0 = 0.f, dyc1 = 0.f;
  if (wlt) { dxc0 = 80.0f * F0[p + 1] - f00;  dxc1 = 80.0f * F1[p + 1] - f10; }
  if (hlt) { dyc0 = 80.0f * F0[p + WW] - f00; dyc1 = 80.0f * F1[p + WW] - f10; }
  float invSc = 1.0f / sqrtf(dxc0*dxc0 + dxc1*dxc1 + dyc0*dyc0 + dyc1*dyc1 + EPS_F);
  float g0 = -(dxc0 + dyc0) * invSc;
  float g1 = -(dxc1 + dyc1) * invSc;
  if (w > 0) {
    float fl0 = 80.0f * F0[p - 1], fl1 = 80.0f * F1[p - 1];
    float dxl0 = f00 - fl0, dxl1 = f10 - fl1;
    float dyl0 = 0.f, dyl1 = 0.f;
    if (hlt) { dyl0 = 80.0f * F0[p + WW - 1] - fl0; dyl1 = 80.0f * F1[p + WW - 1] - fl1; }
    float invSl = 1.0f / sqrtf(dxl0*dxl0 + dxl1*dxl1 + dyl0*dyl0 + dyl1*dyl1 + EPS_F);
    g0 += dxl0 * invSl; g1 += dxl1 * invSl;
  }
  if (h > 0) {
    float fu0 = 80.0f * F0[p - WW], fu1 = 80.0f * F1[p - WW];
    float dyu0 = f00 - fu0, dyu1 = f10 - fu1;
    float dxu0 = 0.f, dxu1 = 0.f;
    if (wlt) { dxu0 = 80.0f * F0[p - WW + 1] - fu0; dxu1 = 80.0f * F1[p - WW + 1] - fu1; }
    float invSu = 1.0f / sqrtf(dxu0*dxu0 + dxu1*dxu1 + dyu0*dyu0 + dyu1*dyu1 + EPS_F);
    g0 += dyu0 * invSu; g1 += dyu1 * invSu;
  }
  g0 *= s1; g1 *= s1;                       // s1 = exp(lw1)/(H*W)*80
  // data term (img channels); img2_internal = ((in2*2-1)+1)/2 (mirror rounding)
  const float* XI = F0 + 2 * HW;
  const float* I2 = in2 + b * 3 * HW;
  float xv0 = XI[p], xv1 = XI[p + HW], xv2 = XI[p + 2 * HW];
  float d0 = (xv0 + 1.0f) * 0.5f - ((I2[p] * 2.0f - 1.0f) + 1.0f) * 0.5f;
  float d1 = (xv1 + 1.0f) * 0.5f - ((I2[p + HW] * 2.0f - 1.0f) + 1.0f) * 0.5f;
  float d2 = (xv2 + 1.0f) * 0.5f - ((I2[p + 2 * HW] * 2.0f - 1.0f) + 1.0f) * 0.5f;
  float A = d0*d0 + d1*d1 + d2*d2;
  float sI = s0 / sqrtf(A + EPS_F);         // s0 = exp(lw0)/(H*W)*0.5
  auto upd = [](float x, float g) {
    g = fminf(fmaxf(g, -0.03f), 0.03f);
    return fminf(fmaxf(x - 10.0f * g, -1.0f), 1.0f);
  };
  xn[0] = upd(x0r, g0);
  xn[1] = upd(x1r, g1);
  xn[2] = upd(xv0, d0 * sI);
  xn[3] = upd(xv1, d1 * sI);
  xn[4] = upd(xv2, d2 * sI);
}

// ---- kernels ----
__global__ void k_init(double* acc, unsigned* keys) {
  int t = threadIdx.x;
  if (t < 200) {                     // split(key(1),200) foldlike: tf(0,1,0,t)
    unsigned o0, o1;
    tf2x32(0u, 1u, 0u, (unsigned)t, o0, o1);
    keys[2 * t] = o0; keys[2 * t + 1] = o1;
  }
  if (t >= 200 && t < 232) acc[t - 200] = 0.0;
}

__global__ __launch_bounds__(256) void k_noise0(const float* __restrict__ init,
    float* __restrict__ Y, const unsigned* __restrict__ keys) {
  int idx = blockIdx.x * 256 + threadIdx.x;
  unsigned o0, o1;
  tf2x32(keys[0], keys[1], 0u, (unsigned)idx, o0, o1);
  float nz = noise_from_bits(o0 ^ o1);
  Y[idx] = fminf(fmaxf(init[idx] + nz, -1.0f), 1.0f);
}

template <bool FINAL>
__global__ __launch_bounds__(256) void k_step(const float* __restrict__ X,
    float* __restrict__ Y, const float* __restrict__ in2,
    const float* __restrict__ lw, const unsigned* __restrict__ keys, int kidx) {
  int tid = blockIdx.x * 256 + threadIdx.x;   // [0, 8*HW)
  int b = tid / HW;
  int p = tid - b * HW;
  int h = p >> 9, w = p & 511;
  float s0 = expf(lw[0]) * INV_HW * 0.5f;
  float s1 = expf(lw[1]) * INV_HW * 80.0f;
  float xn[5];
  grad_update(X, in2, b, p, h, w, s0, s1, xn);
  if (!FINAL) {
    unsigned ka = keys[2 * kidx], kb = keys[2 * kidx + 1];
    int base = b * CHW + p;
#pragma unroll
    for (int c = 0; c < 5; ++c) {
      unsigned o0, o1;
      tf2x32(ka, kb, 0u, (unsigned)(base + c * HW), o0, o1);
      float nz = noise_from_bits(o0 ^ o1);
      Y[base + c * HW] = fminf(fmaxf(xn[c] + nz, -1.0f), 1.0f);
    }
  } else {
    float* outF = Y + OUT_FLOW_OFF + b * 2 * HW;
    outF[p]      = xn[0] * 80.0f;
    outF[HW + p] = xn[1] * 80.0f;
    float* outI = Y + OUT_IMG_OFF + b * 3 * HW;
    outI[p]          = (xn[2] + 1.0f) * 0.5f;
    outI[HW + p]     = (xn[3] + 1.0f) * 0.5f;
    outI[2 * HW + p] = (xn[4] + 1.0f) * 0.5f;
  }
}

__device__ __forceinline__ void block_acc2(double v0, double v1, double* a0, double* a1) {
  for (int off = 32; off > 0; off >>= 1) {
    v0 += __shfl_down(v0, off, 64);
    v1 += __shfl_down(v1, off, 64);
  }
  __shared__ double s0[4], s1[4];
  int lane = threadIdx.x & 63, wv = threadIdx.x >> 6;
  if (lane == 0) { s0[wv] = v0; s1[wv] = v1; }
  __syncthreads();
  if (threadIdx.x == 0) {
    atomicAdd(a0, s0[0] + s0[1] + s0[2] + s0[3]);
    atomicAdd(a1, s1[0] + s1[1] + s1[2] + s1[3]);
  }
}

__global__ __launch_bounds__(256) void k_pos_energy(const float* __restrict__ t1,
    const float* __restrict__ in1, const float* __restrict__ in2,
    double* __restrict__ acc) {
  int blk = blockIdx.x;
  int b = blk / 768;
  int p = (blk - b * 768) * 256 + threadIdx.x;
  int h = p >> 9, w = p & 511;
  const float* T0 = t1 + b * 2 * HW;
  const float* T1 = T0 + HW;
  float f00 = (T0[p] / 80.0f) * 80.0f;     // mirror (t/80)*80 roundtrip
  float f10 = (T1[p] / 80.0f) * 80.0f;
  float dx0 = 0, dx1 = 0, dy0 = 0, dy1 = 0;
  if (w < 511) { dx0 = (T0[p+1]/80.0f)*80.0f - f00;  dx1 = (T1[p+1]/80.0f)*80.0f - f10; }
  if (h < 383) { dy0 = (T0[p+WW]/80.0f)*80.0f - f00; dy1 = (T1[p+WW]/80.0f)*80.0f - f10; }
  double smooth = (double)sqrtf(dx0*dx0 + dx1*dx1 + dy0*dy0 + dy1*dy1 + EPS_F);
  const float* I1 = in1 + b * 3 * HW;
  const float* I2 = in2 + b * 3 * HW;
  float d0 = ((I1[p]*2.0f-1.0f)+1.0f)*0.5f        - ((I2[p]*2.0f-1.0f)+1.0f)*0.5f;
  float d1 = ((I1[p+HW]*2.0f-1.0f)+1.0f)*0.5f     - ((I2[p+HW]*2.0f-1.0f)+1.0f)*0.5f;
  float d2 = ((I1[p+2*HW]*2.0f-1.0f)+1.0f)*0.5f   - ((I2[p+2*HW]*2.0f-1.0f)+1.0f)*0.5f;
  double data = (double)sqrtf(d0*d0 + d1*d1 + d2*d2 + EPS_F);
  block_acc2(data, smooth, &acc[b], &acc[8 + b]);
}

__global__ __launch_bounds__(256) void k_neg_energy(const float* __restrict__ out,
    const float* __restrict__ in2, double* __restrict__ acc) {
  int blk = blockIdx.x;
  int b = blk / 768;
  int p = (blk - b * 768) * 256 + threadIdx.x;
  int h = p >> 9, w = p & 511;
  const float* F0 = out + OUT_FLOW_OFF + b * 2 * HW;   // already = 80*x
  const float* F1 = F0 + HW;
  float f00 = F0[p], f10 = F1[p];
  float dx0 = 0, dx1 = 0, dy0 = 0, dy1 = 0;
  if (w < 511) { dx0 = F0[p + 1] - f00;  dx1 = F1[p + 1] - f10; }
  if (h < 383) { dy0 = F0[p + WW] - f00; dy1 = F1[p + WW] - f10; }
  double smooth = (double)sqrtf(dx0*dx0 + dx1*dx1 + dy0*dy0 + dy1*dy1 + EPS_F);
  const float* I = out + OUT_IMG_OFF + b * 3 * HW;     // already = (x+1)/2
  const float* I2 = in2 + b * 3 * HW;
  float d0 = I[p]        - ((I2[p]*2.0f-1.0f)+1.0f)*0.5f;
  float d1 = I[p+HW]     - ((I2[p+HW]*2.0f-1.0f)+1.0f)*0.5f;
  float d2 = I[p+2*HW]   - ((I2[p+2*HW]*2.0f-1.0f)+1.0f)*0.5f;
  double data = (double)sqrtf(d0*d0 + d1*d1 + d2*d2 + EPS_F);
  block_acc2(data, smooth, &acc[16 + b], &acc[24 + b]);
}

__global__ void k_finalize(const double* __restrict__ acc,
                           const float* __restrict__ lw, float* __restrict__ out) {
  int t = threadIdx.x;
  if (t < 16) {
    int b = t & 7, neg = t >> 3;
    double data   = acc[neg * 16 + b];
    double smooth = acc[neg * 16 + 8 + b];
    double e0 = exp((double)lw[0]), e1 = exp((double)lw[1]);
    out[t] = (float)((e0 * data + e1 * smooth) / 196608.0);
  }
}

extern "C" void kernel_launch(void* const* d_in, const int* in_sizes, int n_in,
                              void* d_out, int out_size, void* d_ws, size_t ws_size,
                              hipStream_t stream) {
  const float* t1  = (const float*)d_in[0];
  const float* in1 = (const float*)d_in[1];
  const float* in2 = (const float*)d_in[2];
  const float* init = (const float*)d_in[3];
  const float* lw  = (const float*)d_in[4];
  float* out = (float*)d_out;

  double* acc = (double*)d_ws;                          // 32 doubles
  unsigned* keys = (unsigned*)((char*)d_ws + 256);      // 400 u32
  size_t need = 2048 + (size_t)NTOT * sizeof(float);
  float* bufA = (ws_size >= need) ? (float*)((char*)d_ws + 2048)
                                  : (float*)d_in[3];    // fallback: reuse init
  float* bufE = out + OUT_FLOW_OFF;                     // even-t states live in d_out

  k_init<<<1, 256, 0, stream>>>(acc, keys);
  k_pos_energy<<<8 * 768, 256, 0, stream>>>(t1, in1, in2, acc);
  k_noise0<<<NTOT / 256, 256, 0, stream>>>(init, bufE, keys);   // n_0 (even)
  for (int t = 0; t < 199; ++t) {
    const float* src = (t % 2 == 0) ? bufE : bufA;
    float* dst       = (t % 2 == 0) ? bufA : bufE;
    k_step<false><<<8 * HW / 256, 256, 0, stream>>>(src, dst, in2, lw, keys, t + 1);
  }
  // n_199 is in bufA (odd); final grad step writes transformed outputs
  k_step<true><<<8 * HW / 256, 256, 0, stream>>>(bufA, out, in2, lw, keys, 0);
  k_neg_energy<<<8 * 768, 256, 0, stream>>>(out, in2, acc);
  k_finalize<<<1, 64, 0, stream>>>(acc, lw, out);
}